// Round 10
// baseline (3102.230 us; speedup 1.0000x reference)
//
#include <hip/hip_runtime.h>
#include <math.h>

#define FHh 100
#define FWw 160
#define CIN 512
#define COUT 512
#define NPIX 16000
#define NANCH 144000
#define PRE_NMS 6000
#define POST_NMS 300
#define EQCAP 8192

#define BM 32
#define BN 128
#define BK 16

// monotonic fp32 -> u32 key
__device__ __forceinline__ unsigned fkey(float x){
  unsigned b = __float_as_uint(x);
  return (b & 0x80000000u) ? ~b : (b | 0x80000000u);
}
// monotonic fp64 -> u64 key
__device__ __forceinline__ unsigned long long dkey(double x){
  unsigned long long u = (unsigned long long)__double_as_longlong(x);
  return (u & 0x8000000000000000ull) ? ~u : (u | 0x8000000000000000ull);
}
__device__ __forceinline__ unsigned long long shfl_u64(unsigned long long x, int lane){
  unsigned lo = (unsigned)x, hi = (unsigned)(x >> 32);
  lo = __shfl(lo, lane, 64);
  hi = __shfl(hi, lane, 64);
  return ((unsigned long long)hi << 32) | lo;
}

// ---------------- fused prep: fm->f64 + head weights ----------------
__global__ __launch_bounds__(256) void prep_all(
    const float* __restrict__ fm, const float* __restrict__ Wc, const float* __restrict__ Wr,
    double* __restrict__ fmd, double* __restrict__ WcT, double* __restrict__ WrT)
{
  const int bid = blockIdx.x;
  if (bid < 8000){
    const int i = bid*256 + threadIdx.x;          // float4 granules
    const float4 v = ((const float4*)fm)[i];
    double2* d = (double2*)(fmd + (size_t)i*4);
    d[0] = make_double2((double)v.x, (double)v.y);
    d[1] = make_double2((double)v.z, (double)v.w);
  } else {
    const int gid = (bid - 8000)*256 + threadIdx.x;
    if (gid < 45*512){
      const int n = gid >> 9, ci = gid & 511;
      if (n < 9) WcT[(size_t)n*512 + ci] = (double)Wc[ci*9 + n];
      else       WrT[(size_t)(n-9)*512 + ci] = (double)Wr[ci*36 + (n-9)];
    }
  }
}

// ---------------- 3x3 conv 512->512 as LDS-staged f64 GEMM ----------------
// grid 2000 (co-major: cg*500 + tile); block 256 = 32 px x 128 co; thread 4 px x 4 co
// 8 blocks/CU (launch_bounds(256,8)); LDS 20 KB/block -> 160 KB/CU exactly.
// accumulation order: chunk-major (tap,k ascending) per output cell -> bit-identical to r7/r8
__global__ __launch_bounds__(256, 8) void conv_gemm(
    const double* __restrict__ fmd, const float* __restrict__ W1,
    const float* __restrict__ b1, double* __restrict__ yd)
{
  __shared__ double As[BK * BM];         // 4 KB, A[k][px]
  __shared__ double Bs[BK * BN];         // 16 KB, B[k][co], lane-linear staged
  const int bid  = blockIdx.x;
  const int cg   = bid / 500;            // 0..3 co-group (co-major for W L2 locality)
  const int tile = bid - cg*500;         // 0..499
  const int row0 = tile / 5;             // one row per tile
  const int xseg = tile - row0*5;
  const int x0   = xseg*32;
  const int co0  = cg*128;

  const int tid = threadIdx.x;
  const int tn = tid & 31;               // co = co0 + tn + 32*j, j=0..3
  const int tm = tid >> 5;               // px = tm*4 + p, p=0..3

  // A staging: lane-consecutive px, two consecutive k per thread (free b64 stores)
  const int apx = tid & 31;              // 0..31
  const int ak  = (tid >> 5) * 2;        // 0,2,...,14
  // B staging: lane-linear, 8 scalar f32 per thread
  const int bkrow = tid >> 7;            // 0..1
  const int bcl   = tid & 127;           // 0..127

  double acc[4][4];
  #pragma unroll
  for (int p = 0; p < 4; ++p)
    #pragma unroll
    for (int j = 0; j < 4; ++j) acc[p][j] = 0.0;

  double pa0, pa1;                       // A prefetch regs
  float pw[8];                           // B prefetch regs

  // load chunk 0 (tap 0 = dy-1,dx-1; k0=0)
  {
    const int gr = row0 - 1, gx = x0 + apx - 1;
    if (gr >= 0 && gx >= 0){             // upper bounds can't trip for chunk 0
      const double2 v = *(const double2*)(fmd + ((size_t)(gr*FWw + gx))*CIN + ak);
      pa0 = v.x; pa1 = v.y;
    } else { pa0 = pa1 = 0.0; }
    const float* wb = W1 + (size_t)co0 + bcl;
    #pragma unroll
    for (int s = 0; s < 8; ++s) pw[s] = wb[(size_t)(2*s + bkrow)*512];
  }

  for (int ch = 0; ch < 288; ++ch){
    __syncthreads();                     // previous compute done; LDS free
    As[(ak+0)*BM + apx] = pa0;
    As[(ak+1)*BM + apx] = pa1;
    #pragma unroll
    for (int s = 0; s < 8; ++s) Bs[s*256 + tid] = (double)pw[s];
    __syncthreads();
    // prefetch next chunk's globals (in flight during compute)
    const int nc = ch + 1;
    if (nc < 288){
      const int tap = nc >> 5;
      const int k0  = (nc & 31) * BK;
      const int dy = tap/3 - 1, dx = tap%3 - 1;
      const int gr = row0 + dy, gx = x0 + apx + dx;
      if (gr >= 0 && gr < FHh && gx >= 0 && gx < FWw){
        const double2 v = *(const double2*)(fmd + ((size_t)(gr*FWw + gx))*CIN + k0 + ak);
        pa0 = v.x; pa1 = v.y;
      } else { pa0 = pa1 = 0.0; }
      const float* wb = W1 + ((size_t)(tap*512 + k0 + bkrow))*512 + co0 + bcl;
      #pragma unroll
      for (int s = 0; s < 8; ++s) pw[s] = wb[(size_t)(2*s)*512];
    }
    // compute: 16 k-steps x (4 px x 4 co) FMAs
    #pragma unroll 4
    for (int k = 0; k < BK; ++k){
      const double2 a01 = *(const double2*)&As[k*BM + tm*4];
      const double2 a23 = *(const double2*)&As[k*BM + tm*4 + 2];
      const double a0 = a01.x, a1 = a01.y, a2 = a23.x, a3 = a23.y;
      #pragma unroll
      for (int j = 0; j < 4; ++j){
        const double bw = Bs[k*BN + tn + 32*j];
        acc[0][j] = fma(a0, bw, acc[0][j]);
        acc[1][j] = fma(a1, bw, acc[1][j]);
        acc[2][j] = fma(a2, bw, acc[2][j]);
        acc[3][j] = fma(a3, bw, acc[3][j]);
      }
    }
  }
  // epilogue: bias + relu + store
  #pragma unroll
  for (int p = 0; p < 4; ++p){
    const int px  = tm*4 + p;
    const int gpx = row0*FWw + x0 + px;
    #pragma unroll
    for (int j = 0; j < 4; ++j){
      const int co = co0 + tn + 32*j;
      yd[(size_t)gpx*CIN + co] = fmax(acc[p][j] + (double)b1[co], 0.0);
    }
  }
}

// ---------------- 1x1 heads (f64): thread = one output n x 4 px ----------------
__global__ __launch_bounds__(256) void head2(
    const double* __restrict__ yd, const double* __restrict__ WcT, const float* __restrict__ bc,
    const double* __restrict__ WrT, const float* __restrict__ br,
    float* __restrict__ out, double* __restrict__ scored, double* __restrict__ regd)
{
  __shared__ double yl[8192];          // 16 px x 512
  const int bid = blockIdx.x, t = threadIdx.x;
  const double2* src = (const double2*)(yd + (size_t)bid * 8192);
  double2* dst = (double2*)yl;
  for (int j = t; j < 4096; j += 256) dst[j] = src[j];
  __syncthreads();
  if (t < 180){
    const int n  = t % 45;
    const int pq = t / 45;             // 0..3 -> px pq*4..pq*4+3
    const double* w = (n < 9) ? (WcT + (size_t)n*512) : (WrT + (size_t)(n-9)*512);
    const double* y0 = yl + (pq*4+0)*512;
    const double* y1 = yl + (pq*4+1)*512;
    const double* y2 = yl + (pq*4+2)*512;
    const double* y3 = yl + (pq*4+3)*512;
    double s0=0.0, s1=0.0, s2=0.0, s3=0.0;
    for (int ci = 0; ci < 512; ++ci){
      const double wv = w[ci];
      s0 = fma(y0[ci], wv, s0);
      s1 = fma(y1[ci], wv, s1);
      s2 = fma(y2[ci], wv, s2);
      s3 = fma(y3[ci], wv, s3);
    }
    const double sv[4] = {s0, s1, s2, s3};
    if (n < 9){
      const double bb = (double)bc[n];
      #pragma unroll
      for (int u = 0; u < 4; ++u){
        const double s = sv[u] + bb;
        const double sig = 1.0 / (1.0 + exp(-s));
        const int gi = (bid*16 + pq*4 + u)*9 + n;
        out[gi] = (float)sig;
        scored[gi] = sig;
      }
    } else {
      const int m = n - 9;
      const double bb = (double)br[m];
      #pragma unroll
      for (int u = 0; u < 4; ++u){
        const double s = sv[u] + bb;
        const int gi = (bid*16 + pq*4 + u)*36 + m;
        out[144000 + gi] = (float)s;
        regd[gi] = s;
      }
    }
  }
}

// ---------------- decode + clip + min-size (f64) + fused hi-histogram ----------------
__global__ __launch_bounds__(256) void decode_hist(
    const float* __restrict__ amap, const double* __restrict__ scored,
    const double* __restrict__ regd, double* __restrict__ boxesd,
    unsigned* __restrict__ key32, unsigned long long* __restrict__ nmskey,
    unsigned* __restrict__ hist)
{
  const int i = blockIdx.x*256 + threadIdx.x;
  if (i >= NANCH) return;
  const double a0=(double)amap[4*i+0], a1=(double)amap[4*i+1];
  const double a2=(double)amap[4*i+2], a3=(double)amap[4*i+3];
  const double d0=regd[4*i+0], d1=regd[4*i+1], d2=regd[4*i+2], d3=regd[4*i+3];
  const double ah = a2 - a0, aw = a3 - a1;
  const double cy = a0 + 0.5*ah + d0*ah;
  const double cx = a1 + 0.5*aw + d1*aw;
  const double h = ah * exp(d2), w = aw * exp(d3);
  double y1 = cy - 0.5*h, x1 = cx - 0.5*w, y2 = cy + 0.5*h, x2 = cx + 0.5*w;
  y1 = fmax(y1, 0.0); x1 = fmax(x1, 0.0);
  y2 = fmin(y2, 1600.0); x2 = fmin(x2, 2560.0);
  boxesd[4*i+0]=y1; boxesd[4*i+1]=x1; boxesd[4*i+2]=y2; boxesd[4*i+3]=x2;
  const double obj = scored[i];
  const bool ok = (y2 - y1 >= 16.0) && (x2 - x1 >= 16.0);
  const unsigned k32 = fkey((float)obj);
  key32[i] = k32;
  nmskey[i] = ok ? dkey(obj) : dkey(-1e9);
  atomicAdd(&hist[k32 >> 16], 1u);
}

// ---------------- top-6000 radix select on f32-rounded keys ----------------
__global__ __launch_bounds__(1024) void scan_hi(const unsigned* __restrict__ hist, int* __restrict__ meta){
  __shared__ unsigned part[1024];
  const int t = threadIdx.x;
  unsigned s = 0;
  for (int j = 0; j < 64; ++j) s += hist[65535 - (t*64 + j)];
  part[t] = s;
  __syncthreads();
  for (int off = 1; off < 1024; off <<= 1){
    unsigned v = (t >= off) ? part[t - off] : 0u;
    __syncthreads();
    part[t] += v;
    __syncthreads();
  }
  const unsigned incl = part[t], excl = incl - s;
  if (excl < PRE_NMS && incl >= PRE_NMS){
    unsigned cum = excl;
    for (int j = 0; j < 64; ++j){
      const int bin = 65535 - (t*64 + j);
      const unsigned c = hist[bin];
      if (cum + c >= PRE_NMS){ meta[0] = bin; meta[1] = (int)cum; break; }
      cum += c;
    }
  }
}

__global__ __launch_bounds__(256) void hist_lo(const unsigned* __restrict__ key,
                                               const int* __restrict__ meta, unsigned* __restrict__ hist){
  const int i = blockIdx.x*256 + threadIdx.x;
  if (i < NANCH){
    const unsigned k = key[i];
    if ((int)(k >> 16) == meta[0]) atomicAdd(&hist[k & 0xFFFFu], 1u);
  }
}

__global__ __launch_bounds__(1024) void scan_lo(const unsigned* __restrict__ hist, int* __restrict__ meta){
  __shared__ unsigned part[1024];
  const int t = threadIdx.x;
  const unsigned G0 = (unsigned)meta[1];
  unsigned s = 0;
  for (int j = 0; j < 64; ++j) s += hist[65535 - (t*64 + j)];
  part[t] = s;
  __syncthreads();
  for (int off = 1; off < 1024; off <<= 1){
    unsigned v = (t >= off) ? part[t - off] : 0u;
    __syncthreads();
    part[t] += v;
    __syncthreads();
  }
  const unsigned incl = G0 + part[t], excl = incl - s;
  if (excl < PRE_NMS && incl >= PRE_NMS){
    unsigned cum = excl;
    for (int j = 0; j < 64; ++j){
      const int bin = 65535 - (t*64 + j);
      const unsigned c = hist[bin];
      if (cum + c >= PRE_NMS){
        meta[2] = (int)(((unsigned)meta[0] << 16) | (unsigned)bin);
        meta[3] = (int)cum;
        meta[4] = PRE_NMS - (int)cum;
        break;
      }
      cum += c;
    }
  }
}

__global__ __launch_bounds__(256) void compact_k(
    const unsigned* __restrict__ key, const unsigned long long* __restrict__ nmskey,
    const double* __restrict__ boxesd, const int* __restrict__ meta,
    int* __restrict__ cnt, double* __restrict__ selboxd,
    unsigned long long* __restrict__ selkey, int* __restrict__ eqidx)
{
  const int i = blockIdx.x*256 + threadIdx.x;
  if (i >= NANCH) return;
  const unsigned k = key[i];
  const unsigned T = (unsigned)meta[2];
  if (k > T){
    const int s = atomicAdd(&cnt[0], 1);
    selboxd[4*s+0]=boxesd[4*i+0]; selboxd[4*s+1]=boxesd[4*i+1];
    selboxd[4*s+2]=boxesd[4*i+2]; selboxd[4*s+3]=boxesd[4*i+3];
    selkey[s] = nmskey[i];
  } else if (k == T){
    const int e = atomicAdd(&cnt[1], 1);
    if (e < EQCAP) eqidx[e] = i;
  }
}

__global__ __launch_bounds__(256) void rankeq(
    const double* __restrict__ scored, const double* __restrict__ boxesd,
    const unsigned long long* __restrict__ nmskey,
    const int* __restrict__ meta, const int* __restrict__ cnt,
    const int* __restrict__ eqidx, double* __restrict__ selboxd,
    unsigned long long* __restrict__ selkey)
{
  __shared__ int eq[EQCAP];
  const int t = threadIdx.x;
  int E = cnt[1]; if (E > EQCAP) E = EQCAP;
  const int R = meta[4], G2 = meta[3];
  for (int j = t; j < E; j += 256) eq[j] = eqidx[j];
  __syncthreads();
  for (int j = t; j < E; j += 256){
    const int my = eq[j];
    const double smy = scored[my];
    int rank = 0;
    for (int k2 = 0; k2 < E; ++k2){
      const int ok = eq[k2];
      const double sk = scored[ok];
      rank += ((sk > smy) || (sk == smy && ok < my)) ? 1 : 0;
    }
    if (rank < R){
      const int s = G2 + rank;
      selboxd[4*s+0]=boxesd[4*my+0]; selboxd[4*s+1]=boxesd[4*my+1];
      selboxd[4*s+2]=boxesd[4*my+2]; selboxd[4*s+3]=boxesd[4*my+3];
      selkey[s] = nmskey[my];
    }
  }
}

// ---------------- rank-by-counting scatter ----------------
__global__ __launch_bounds__(256) void rank_scatter(
    const unsigned long long* __restrict__ selkey, const double* __restrict__ selboxd,
    unsigned long long* __restrict__ skeys, double* __restrict__ sboxd)
{
  __shared__ unsigned long long k[PRE_NMS];
  const int t = threadIdx.x;
  for (int j = t; j < PRE_NMS; j += 256) k[j] = selkey[j];
  __syncthreads();
  const int j = blockIdx.x*256 + t;
  if (j >= PRE_NMS) return;
  const unsigned long long kj = k[j];
  int r = 0;
  for (int i = 0; i < PRE_NMS; i += 4){
    r += (int)((k[i+0] > kj) || (k[i+0] == kj && (i+0) < j));
    r += (int)((k[i+1] > kj) || (k[i+1] == kj && (i+1) < j));
    r += (int)((k[i+2] > kj) || (k[i+2] == kj && (i+2) < j));
    r += (int)((k[i+3] > kj) || (k[i+3] == kj && (i+3) < j));
  }
  skeys[r] = kj;
  sboxd[(size_t)r*4+0] = selboxd[(size_t)j*4+0];
  sboxd[(size_t)r*4+1] = selboxd[(size_t)j*4+1];
  sboxd[(size_t)r*4+2] = selboxd[(size_t)j*4+2];
  sboxd[(size_t)r*4+3] = selboxd[(size_t)j*4+3];
}

// ---------------- 6000x6000 IOU suppression bitmap ----------------
__global__ __launch_bounds__(256) void iou_bitmap(
    const double* __restrict__ sboxd, unsigned long long* __restrict__ rowbits)
{
  __shared__ double cbx[4096];           // 1024 col boxes
  const int g = blockIdx.y;              // 0..5 word-groups
  const int r0 = blockIdx.x * 16;
  const int t = threadIdx.x;
  const int cbase = g * 1024;
  for (int e = t; e < 4096; e += 256){
    const int bi = cbase + (e >> 2);
    cbx[e] = (bi < PRE_NMS) ? sboxd[(size_t)bi*4 + (e & 3)] : 0.0;
  }
  __syncthreads();
  const int r = r0 + (t >> 4);
  const int w = t & 15;
  const double by1 = sboxd[(size_t)r*4+0], bx1 = sboxd[(size_t)r*4+1];
  const double by2 = sboxd[(size_t)r*4+2], bx2 = sboxd[(size_t)r*4+3];
  const double a1 = fmax(by2-by1, 0.0) * fmax(bx2-bx1, 0.0);
  unsigned long long bits = 0ull;
  for (int b = 0; b < 64; ++b){
    const int bcol = (b + w) & 63;
    const int j = cbase + w*64 + bcol;
    if (j < PRE_NMS){
      const int ce = (w*64 + bcol)*4;
      const double c0 = cbx[ce+0], c1 = cbx[ce+1], c2 = cbx[ce+2], c3 = cbx[ce+3];
      const double yy1 = fmax(by1, c0), xx1 = fmax(bx1, c1);
      const double yy2 = fmin(by2, c2), xx2 = fmin(bx2, c3);
      const double inter = fmax(yy2-yy1, 0.0) * fmax(xx2-xx1, 0.0);
      const double a2 = fmax(c2-c0, 0.0) * fmax(c3-c1, 0.0);
      const double iou = inter / (a1 + a2 - inter + 1e-8);
      if (iou > 0.7) bits |= (1ull << bcol);
    }
  }
  rowbits[(size_t)r*128 + g*16 + w] = bits;
}

// ---------------- greedy scan with suppression bitmap ----------------
__global__ __launch_bounds__(64) void greedy(
    const unsigned long long* __restrict__ skeys, const double* __restrict__ sboxd,
    const unsigned long long* __restrict__ rowbits, float* __restrict__ outp)
{
  const int t = threadIdx.x;
  const unsigned long long KEYTH = dkey(-5.0e8);
  int bad = PRE_NMS;
  for (int j = t; j < PRE_NMS; j += 64){
    if (skeys[j] <= KEYTH){ bad = j; break; }
  }
  #pragma unroll
  for (int off = 32; off > 0; off >>= 1){
    const int o = __shfl_down(bad, off, 64);
    bad = (o < bad) ? o : bad;
  }
  const int ilim = __builtin_amdgcn_readfirstlane(bad);

  unsigned long long s0 = 0ull, s1 = 0ull;
  int emitted = 0;
  for (int i = 0; i < ilim && emitted < POST_NMS; ++i){
    const int w = i >> 6, b = i & 63;
    const unsigned long long w0 = shfl_u64(s0, w & 63);
    const unsigned long long w1 = shfl_u64(s1, (w - 64) & 63);
    const unsigned long long word = (w < 64) ? w0 : w1;
    if (!((word >> b) & 1ull)){
      if (t < 4) outp[4*emitted + t] = (float)sboxd[(size_t)i*4 + t];
      s0 |= rowbits[(size_t)i*128 + t];
      if (t < 30) s1 |= rowbits[(size_t)i*128 + 64 + t];
      ++emitted;
    }
  }
  for (int r = emitted; r < POST_NMS; ++r)
    if (t < 4) outp[4*r + t] = 0.f;
}

extern "C" void kernel_launch(void* const* d_in, const int* in_sizes, int n_in,
                              void* d_out, int out_size, void* d_ws, size_t ws_size,
                              hipStream_t stream)
{
  const float* fm   = (const float*)d_in[1];
  const float* amap = (const float*)d_in[2];
  const float* W1   = (const float*)d_in[4];
  const float* b1   = (const float*)d_in[5];
  const float* Wc   = (const float*)d_in[6];
  const float* bc   = (const float*)d_in[7];
  const float* Wr   = (const float*)d_in[8];
  const float* br   = (const float*)d_in[9];
  float* out = (float*)d_out;

  char* base = (char*)d_ws;
  size_t off = 0;
  auto A = [&](size_t n) -> char* {
    char* p = base + off;
    off = (off + n + 255) & ~(size_t)255;
    return p;
  };
  double* yd      = (double*)A(65536000);
  double* fmd     = (double*)A(65536000);
  double* WcT     = (double*)A(36864);
  double* WrT     = (double*)A(147456);
  double* scored  = (double*)A(1152000);
  double* regd    = (double*)A(4608000);
  unsigned* histc = (unsigned*)A(524328);        // hist1|hist2|cnt|meta contiguous
  double* boxesd              = (double*)A(4608000);
  unsigned long long* nmskey  = (unsigned long long*)A(1152000);
  unsigned* key32             = (unsigned*)A(576000);
  double* selboxd             = (double*)A(192000);
  unsigned long long* selkey  = (unsigned long long*)A(48000);
  unsigned long long* skeys   = (unsigned long long*)A(48000);
  double* sboxd               = (double*)A(192000);
  unsigned long long* rowbits = (unsigned long long*)A(6144000);
  int* eqidx                  = (int*)A(32768);

  unsigned* hist1 = histc;
  unsigned* hist2 = histc + 65536;
  int* cnt        = (int*)(histc + 131072);
  int* meta       = cnt + 2;

  hipMemsetAsync(histc, 0, (size_t)524328, stream);

  hipLaunchKernelGGL(prep_all, dim3(8090), dim3(256), 0, stream,
                     fm, Wc, Wr, fmd, WcT, WrT);
  hipLaunchKernelGGL(conv_gemm, dim3(2000), dim3(256), 0, stream, fmd, W1, b1, yd);
  hipLaunchKernelGGL(head2, dim3(1000), dim3(256), 0, stream, yd, WcT, bc, WrT, br, out, scored, regd);
  hipLaunchKernelGGL(decode_hist, dim3((NANCH + 255)/256), dim3(256), 0, stream,
                     amap, scored, regd, boxesd, key32, nmskey, hist1);
  hipLaunchKernelGGL(scan_hi, dim3(1), dim3(1024), 0, stream, hist1, meta);
  hipLaunchKernelGGL(hist_lo, dim3((NANCH + 255)/256), dim3(256), 0, stream, key32, meta, hist2);
  hipLaunchKernelGGL(scan_lo, dim3(1), dim3(1024), 0, stream, hist2, meta);
  hipLaunchKernelGGL(compact_k, dim3((NANCH + 255)/256), dim3(256), 0, stream,
                     key32, nmskey, boxesd, meta, cnt, selboxd, selkey, eqidx);
  hipLaunchKernelGGL(rankeq, dim3(1), dim3(256), 0, stream,
                     scored, boxesd, nmskey, meta, cnt, eqidx, selboxd, selkey);
  hipLaunchKernelGGL(rank_scatter, dim3((PRE_NMS + 255)/256), dim3(256), 0, stream,
                     selkey, selboxd, skeys, sboxd);
  hipLaunchKernelGGL(iou_bitmap, dim3(375, 6), dim3(256), 0, stream, sboxd, rowbits);
  hipLaunchKernelGGL(greedy, dim3(1), dim3(64), 0, stream, skeys, sboxd, rowbits, out + 720000);
}

// Round 11
// 2689.822 us; speedup vs baseline: 1.1533x; 1.1533x over previous
//
#include <hip/hip_runtime.h>
#include <math.h>

#define FHh 100
#define FWw 160
#define CIN 512
#define COUT 512
#define NPIX 16000
#define NANCH 144000
#define PRE_NMS 6000
#define POST_NMS 300
#define EQCAP 8192

#define BM 64
#define BN 128
#define BK 16
#define ASTRIDE 66   // padded A row stride (2-way-free staging, conflict-free reads)

// monotonic fp32 -> u32 key
__device__ __forceinline__ unsigned fkey(float x){
  unsigned b = __float_as_uint(x);
  return (b & 0x80000000u) ? ~b : (b | 0x80000000u);
}
// monotonic fp64 -> u64 key
__device__ __forceinline__ unsigned long long dkey(double x){
  unsigned long long u = (unsigned long long)__double_as_longlong(x);
  return (u & 0x8000000000000000ull) ? ~u : (u | 0x8000000000000000ull);
}
__device__ __forceinline__ unsigned long long shfl_u64(unsigned long long x, int lane){
  unsigned lo = (unsigned)x, hi = (unsigned)(x >> 32);
  lo = __shfl(lo, lane, 64);
  hi = __shfl(hi, lane, 64);
  return ((unsigned long long)hi << 32) | lo;
}

// ---------------- fused prep: fm->f64 + head weights ----------------
__global__ __launch_bounds__(256) void prep_all(
    const float* __restrict__ fm, const float* __restrict__ Wc, const float* __restrict__ Wr,
    double* __restrict__ fmd, double* __restrict__ WcT, double* __restrict__ WrT)
{
  const int bid = blockIdx.x;
  if (bid < 8000){
    const int i = bid*256 + threadIdx.x;          // float4 granules
    const float4 v = ((const float4*)fm)[i];
    double2* d = (double2*)(fmd + (size_t)i*4);
    d[0] = make_double2((double)v.x, (double)v.y);
    d[1] = make_double2((double)v.z, (double)v.w);
  } else {
    const int gid = (bid - 8000)*256 + threadIdx.x;
    if (gid < 45*512){
      const int n = gid >> 9, ci = gid & 511;
      if (n < 9) WcT[(size_t)n*512 + ci] = (double)Wc[ci*9 + n];
      else       WrT[(size_t)(n-9)*512 + ci] = (double)Wr[ci*36 + (n-9)];
    }
  }
}

// ---------------- 3x3 conv 512->512 as LDS-staged f64 GEMM (r8 structure, B reads as double2) ----------------
// grid 1000 (co-major: cg*250 + tile); block 256 = 64 px x 128 co; BK=16; 288 chunks (9 taps x 32)
// per thread 4 px x 8 co; co = co0 + tn*2 + 32*j + c  (b128 B reads, conflict-free)
// accumulation order per output cell: chunk-major, k-ascending -> bit-identical to r7/r8
__global__ __launch_bounds__(256, 4) void conv_gemm(
    const double* __restrict__ fmd, const float* __restrict__ W1,
    const float* __restrict__ b1, double* __restrict__ yd)
{
  __shared__ double As[BK * ASTRIDE];    // 8.25 KB, A[k][px], padded
  __shared__ double Bs[BK * BN];         // 16 KB, B[k][co], lane-linear staged
  const int bid  = blockIdx.x;
  const int cg   = bid / 250;            // 0..3 co-group (co-major for W L2 locality)
  const int tile = bid - cg*250;         // 0..249
  const int rp   = tile / 5;
  const int xseg = tile - rp*5;
  const int x0   = xseg*32;
  const int row0 = rp*2;
  const int co0  = cg*128;

  const int tid = threadIdx.x;
  const int tn = tid & 15;               // co = co0 + tn*2 + 32*j + c
  const int tm = tid >> 4;               // pxs = tm*4 .. +3

  // A staging map (coalesced global: 4 consecutive k per px)
  const int apx = tid >> 2;              // 0..63
  const int aks = (tid & 3) * 4;         // k 0..15 in 4s
  const int ah  = apx >> 5;              // half-row
  const int ac  = apx & 31;
  // B staging map (lane-linear LDS, coalesced global scalar reads)
  const int bkrow = tid >> 7;            // 0..1
  const int bcl   = tid & 127;           // 0..127

  double acc[4][8];
  #pragma unroll
  for (int p = 0; p < 4; ++p)
    #pragma unroll
    for (int j = 0; j < 8; ++j) acc[p][j] = 0.0;

  double pa0, pa1, pa2, pa3;             // A prefetch regs
  float pw[8];                           // B prefetch regs

  // load chunk 0 (tap 0 = dy-1,dx-1; k0=0)
  {
    const int gr = row0 + ah - 1, gx = x0 + ac - 1;
    if (gr >= 0 && gx >= 0){             // upper bounds can't trip for chunk 0
      const double* p = fmd + ((size_t)(gr*FWw + gx))*CIN + aks;
      pa0 = p[0]; pa1 = p[1]; pa2 = p[2]; pa3 = p[3];
    } else { pa0 = pa1 = pa2 = pa3 = 0.0; }
    const float* wb = W1 + (size_t)co0 + bcl;
    #pragma unroll
    for (int s = 0; s < 8; ++s) pw[s] = wb[(size_t)(2*s + bkrow)*512];
  }

  for (int ch = 0; ch < 288; ++ch){
    __syncthreads();                     // previous compute done; LDS free
    As[(aks+0)*ASTRIDE + apx] = pa0;
    As[(aks+1)*ASTRIDE + apx] = pa1;
    As[(aks+2)*ASTRIDE + apx] = pa2;
    As[(aks+3)*ASTRIDE + apx] = pa3;
    #pragma unroll
    for (int s = 0; s < 8; ++s) Bs[s*256 + tid] = (double)pw[s];
    __syncthreads();
    // prefetch next chunk's globals (in flight during compute)
    const int nc = ch + 1;
    if (nc < 288){
      const int tap = nc >> 5;
      const int k0  = (nc & 31) * BK;
      const int dy = tap/3 - 1, dx = tap%3 - 1;
      const int gr = row0 + ah + dy, gx = x0 + ac + dx;
      if (gr >= 0 && gr < FHh && gx >= 0 && gx < FWw){
        const double* p = fmd + ((size_t)(gr*FWw + gx))*CIN + k0 + aks;
        pa0 = p[0]; pa1 = p[1]; pa2 = p[2]; pa3 = p[3];
      } else { pa0 = pa1 = pa2 = pa3 = 0.0; }
      const float* wb = W1 + ((size_t)(tap*512 + k0 + bkrow))*512 + co0 + bcl;
      #pragma unroll
      for (int s = 0; s < 8; ++s) pw[s] = wb[(size_t)(2*s)*512];
    }
    // compute: 16 k-steps x (4 px x 8 co) FMAs; B read as double2 (b128, conflict-free)
    #pragma unroll 4
    for (int k = 0; k < BK; ++k){
      const double2 a01 = *(const double2*)&As[k*ASTRIDE + tm*4];
      const double2 a23 = *(const double2*)&As[k*ASTRIDE + tm*4 + 2];
      const double a0 = a01.x, a1 = a01.y, a2 = a23.x, a3 = a23.y;
      #pragma unroll
      for (int j = 0; j < 4; ++j){
        const double2 bw = *(const double2*)&Bs[k*BN + tn*2 + 32*j];
        acc[0][2*j+0] = fma(a0, bw.x, acc[0][2*j+0]);
        acc[1][2*j+0] = fma(a1, bw.x, acc[1][2*j+0]);
        acc[2][2*j+0] = fma(a2, bw.x, acc[2][2*j+0]);
        acc[3][2*j+0] = fma(a3, bw.x, acc[3][2*j+0]);
        acc[0][2*j+1] = fma(a0, bw.y, acc[0][2*j+1]);
        acc[1][2*j+1] = fma(a1, bw.y, acc[1][2*j+1]);
        acc[2][2*j+1] = fma(a2, bw.y, acc[2][2*j+1]);
        acc[3][2*j+1] = fma(a3, bw.y, acc[3][2*j+1]);
      }
    }
  }
  // epilogue: bias + relu + store (co pairs -> coalesced 16B/lane)
  #pragma unroll
  for (int p = 0; p < 4; ++p){
    const int px  = tm*4 + p;
    const int gpx = (row0 + (px >> 5))*FWw + x0 + (px & 31);
    #pragma unroll
    for (int j = 0; j < 4; ++j){
      const int co = co0 + tn*2 + 32*j;
      double2 v;
      v.x = fmax(acc[p][2*j+0] + (double)b1[co+0], 0.0);
      v.y = fmax(acc[p][2*j+1] + (double)b1[co+1], 0.0);
      *(double2*)&yd[(size_t)gpx*CIN + co] = v;
    }
  }
}

// ---------------- 1x1 heads (f64): thread = one output n x 4 px ----------------
__global__ __launch_bounds__(256) void head2(
    const double* __restrict__ yd, const double* __restrict__ WcT, const float* __restrict__ bc,
    const double* __restrict__ WrT, const float* __restrict__ br,
    float* __restrict__ out, double* __restrict__ scored, double* __restrict__ regd)
{
  __shared__ double yl[8192];          // 16 px x 512
  const int bid = blockIdx.x, t = threadIdx.x;
  const double2* src = (const double2*)(yd + (size_t)bid * 8192);
  double2* dst = (double2*)yl;
  for (int j = t; j < 4096; j += 256) dst[j] = src[j];
  __syncthreads();
  if (t < 180){
    const int n  = t % 45;
    const int pq = t / 45;             // 0..3 -> px pq*4..pq*4+3
    const double* w = (n < 9) ? (WcT + (size_t)n*512) : (WrT + (size_t)(n-9)*512);
    const double* y0 = yl + (pq*4+0)*512;
    const double* y1 = yl + (pq*4+1)*512;
    const double* y2 = yl + (pq*4+2)*512;
    const double* y3 = yl + (pq*4+3)*512;
    double s0=0.0, s1=0.0, s2=0.0, s3=0.0;
    for (int ci = 0; ci < 512; ++ci){
      const double wv = w[ci];
      s0 = fma(y0[ci], wv, s0);
      s1 = fma(y1[ci], wv, s1);
      s2 = fma(y2[ci], wv, s2);
      s3 = fma(y3[ci], wv, s3);
    }
    const double sv[4] = {s0, s1, s2, s3};
    if (n < 9){
      const double bb = (double)bc[n];
      #pragma unroll
      for (int u = 0; u < 4; ++u){
        const double s = sv[u] + bb;
        const double sig = 1.0 / (1.0 + exp(-s));
        const int gi = (bid*16 + pq*4 + u)*9 + n;
        out[gi] = (float)sig;
        scored[gi] = sig;
      }
    } else {
      const int m = n - 9;
      const double bb = (double)br[m];
      #pragma unroll
      for (int u = 0; u < 4; ++u){
        const double s = sv[u] + bb;
        const int gi = (bid*16 + pq*4 + u)*36 + m;
        out[144000 + gi] = (float)s;
        regd[gi] = s;
      }
    }
  }
}

// ---------------- decode + clip + min-size (f64) + fused hi-histogram ----------------
__global__ __launch_bounds__(256) void decode_hist(
    const float* __restrict__ amap, const double* __restrict__ scored,
    const double* __restrict__ regd, double* __restrict__ boxesd,
    unsigned* __restrict__ key32, unsigned long long* __restrict__ nmskey,
    unsigned* __restrict__ hist)
{
  const int i = blockIdx.x*256 + threadIdx.x;
  if (i >= NANCH) return;
  const double a0=(double)amap[4*i+0], a1=(double)amap[4*i+1];
  const double a2=(double)amap[4*i+2], a3=(double)amap[4*i+3];
  const double d0=regd[4*i+0], d1=regd[4*i+1], d2=regd[4*i+2], d3=regd[4*i+3];
  const double ah = a2 - a0, aw = a3 - a1;
  const double cy = a0 + 0.5*ah + d0*ah;
  const double cx = a1 + 0.5*aw + d1*aw;
  const double h = ah * exp(d2), w = aw * exp(d3);
  double y1 = cy - 0.5*h, x1 = cx - 0.5*w, y2 = cy + 0.5*h, x2 = cx + 0.5*w;
  y1 = fmax(y1, 0.0); x1 = fmax(x1, 0.0);
  y2 = fmin(y2, 1600.0); x2 = fmin(x2, 2560.0);
  boxesd[4*i+0]=y1; boxesd[4*i+1]=x1; boxesd[4*i+2]=y2; boxesd[4*i+3]=x2;
  const double obj = scored[i];
  const bool ok = (y2 - y1 >= 16.0) && (x2 - x1 >= 16.0);
  const unsigned k32 = fkey((float)obj);
  key32[i] = k32;
  nmskey[i] = ok ? dkey(obj) : dkey(-1e9);
  atomicAdd(&hist[k32 >> 16], 1u);
}

// ---------------- top-6000 radix select on f32-rounded keys ----------------
__global__ __launch_bounds__(1024) void scan_hi(const unsigned* __restrict__ hist, int* __restrict__ meta){
  __shared__ unsigned part[1024];
  const int t = threadIdx.x;
  unsigned s = 0;
  for (int j = 0; j < 64; ++j) s += hist[65535 - (t*64 + j)];
  part[t] = s;
  __syncthreads();
  for (int off = 1; off < 1024; off <<= 1){
    unsigned v = (t >= off) ? part[t - off] : 0u;
    __syncthreads();
    part[t] += v;
    __syncthreads();
  }
  const unsigned incl = part[t], excl = incl - s;
  if (excl < PRE_NMS && incl >= PRE_NMS){
    unsigned cum = excl;
    for (int j = 0; j < 64; ++j){
      const int bin = 65535 - (t*64 + j);
      const unsigned c = hist[bin];
      if (cum + c >= PRE_NMS){ meta[0] = bin; meta[1] = (int)cum; break; }
      cum += c;
    }
  }
}

__global__ __launch_bounds__(256) void hist_lo(const unsigned* __restrict__ key,
                                               const int* __restrict__ meta, unsigned* __restrict__ hist){
  const int i = blockIdx.x*256 + threadIdx.x;
  if (i < NANCH){
    const unsigned k = key[i];
    if ((int)(k >> 16) == meta[0]) atomicAdd(&hist[k & 0xFFFFu], 1u);
  }
}

__global__ __launch_bounds__(1024) void scan_lo(const unsigned* __restrict__ hist, int* __restrict__ meta){
  __shared__ unsigned part[1024];
  const int t = threadIdx.x;
  const unsigned G0 = (unsigned)meta[1];
  unsigned s = 0;
  for (int j = 0; j < 64; ++j) s += hist[65535 - (t*64 + j)];
  part[t] = s;
  __syncthreads();
  for (int off = 1; off < 1024; off <<= 1){
    unsigned v = (t >= off) ? part[t - off] : 0u;
    __syncthreads();
    part[t] += v;
    __syncthreads();
  }
  const unsigned incl = G0 + part[t], excl = incl - s;
  if (excl < PRE_NMS && incl >= PRE_NMS){
    unsigned cum = excl;
    for (int j = 0; j < 64; ++j){
      const int bin = 65535 - (t*64 + j);
      const unsigned c = hist[bin];
      if (cum + c >= PRE_NMS){
        meta[2] = (int)(((unsigned)meta[0] << 16) | (unsigned)bin);
        meta[3] = (int)cum;
        meta[4] = PRE_NMS - (int)cum;
        break;
      }
      cum += c;
    }
  }
}

__global__ __launch_bounds__(256) void compact_k(
    const unsigned* __restrict__ key, const unsigned long long* __restrict__ nmskey,
    const double* __restrict__ boxesd, const int* __restrict__ meta,
    int* __restrict__ cnt, double* __restrict__ selboxd,
    unsigned long long* __restrict__ selkey, int* __restrict__ eqidx)
{
  const int i = blockIdx.x*256 + threadIdx.x;
  if (i >= NANCH) return;
  const unsigned k = key[i];
  const unsigned T = (unsigned)meta[2];
  if (k > T){
    const int s = atomicAdd(&cnt[0], 1);
    selboxd[4*s+0]=boxesd[4*i+0]; selboxd[4*s+1]=boxesd[4*i+1];
    selboxd[4*s+2]=boxesd[4*i+2]; selboxd[4*s+3]=boxesd[4*i+3];
    selkey[s] = nmskey[i];
  } else if (k == T){
    const int e = atomicAdd(&cnt[1], 1);
    if (e < EQCAP) eqidx[e] = i;
  }
}

__global__ __launch_bounds__(256) void rankeq(
    const double* __restrict__ scored, const double* __restrict__ boxesd,
    const unsigned long long* __restrict__ nmskey,
    const int* __restrict__ meta, const int* __restrict__ cnt,
    const int* __restrict__ eqidx, double* __restrict__ selboxd,
    unsigned long long* __restrict__ selkey)
{
  __shared__ int eq[EQCAP];
  const int t = threadIdx.x;
  int E = cnt[1]; if (E > EQCAP) E = EQCAP;
  const int R = meta[4], G2 = meta[3];
  for (int j = t; j < E; j += 256) eq[j] = eqidx[j];
  __syncthreads();
  for (int j = t; j < E; j += 256){
    const int my = eq[j];
    const double smy = scored[my];
    int rank = 0;
    for (int k2 = 0; k2 < E; ++k2){
      const int ok = eq[k2];
      const double sk = scored[ok];
      rank += ((sk > smy) || (sk == smy && ok < my)) ? 1 : 0;
    }
    if (rank < R){
      const int s = G2 + rank;
      selboxd[4*s+0]=boxesd[4*my+0]; selboxd[4*s+1]=boxesd[4*my+1];
      selboxd[4*s+2]=boxesd[4*my+2]; selboxd[4*s+3]=boxesd[4*my+3];
      selkey[s] = nmskey[my];
    }
  }
}

// ---------------- rank-by-counting scatter ----------------
__global__ __launch_bounds__(256) void rank_scatter(
    const unsigned long long* __restrict__ selkey, const double* __restrict__ selboxd,
    unsigned long long* __restrict__ skeys, double* __restrict__ sboxd)
{
  __shared__ unsigned long long k[PRE_NMS];
  const int t = threadIdx.x;
  for (int j = t; j < PRE_NMS; j += 256) k[j] = selkey[j];
  __syncthreads();
  const int j = blockIdx.x*256 + t;
  if (j >= PRE_NMS) return;
  const unsigned long long kj = k[j];
  int r = 0;
  for (int i = 0; i < PRE_NMS; i += 4){
    r += (int)((k[i+0] > kj) || (k[i+0] == kj && (i+0) < j));
    r += (int)((k[i+1] > kj) || (k[i+1] == kj && (i+1) < j));
    r += (int)((k[i+2] > kj) || (k[i+2] == kj && (i+2) < j));
    r += (int)((k[i+3] > kj) || (k[i+3] == kj && (i+3) < j));
  }
  skeys[r] = kj;
  sboxd[(size_t)r*4+0] = selboxd[(size_t)j*4+0];
  sboxd[(size_t)r*4+1] = selboxd[(size_t)j*4+1];
  sboxd[(size_t)r*4+2] = selboxd[(size_t)j*4+2];
  sboxd[(size_t)r*4+3] = selboxd[(size_t)j*4+3];
}

// ---------------- 6000x6000 IOU suppression bitmap ----------------
__global__ __launch_bounds__(256) void iou_bitmap(
    const double* __restrict__ sboxd, unsigned long long* __restrict__ rowbits)
{
  __shared__ double cbx[4096];           // 1024 col boxes
  const int g = blockIdx.y;              // 0..5 word-groups
  const int r0 = blockIdx.x * 16;
  const int t = threadIdx.x;
  const int cbase = g * 1024;
  for (int e = t; e < 4096; e += 256){
    const int bi = cbase + (e >> 2);
    cbx[e] = (bi < PRE_NMS) ? sboxd[(size_t)bi*4 + (e & 3)] : 0.0;
  }
  __syncthreads();
  const int r = r0 + (t >> 4);
  const int w = t & 15;
  const double by1 = sboxd[(size_t)r*4+0], bx1 = sboxd[(size_t)r*4+1];
  const double by2 = sboxd[(size_t)r*4+2], bx2 = sboxd[(size_t)r*4+3];
  const double a1 = fmax(by2-by1, 0.0) * fmax(bx2-bx1, 0.0);
  unsigned long long bits = 0ull;
  for (int b = 0; b < 64; ++b){
    const int bcol = (b + w) & 63;
    const int j = cbase + w*64 + bcol;
    if (j < PRE_NMS){
      const int ce = (w*64 + bcol)*4;
      const double c0 = cbx[ce+0], c1 = cbx[ce+1], c2 = cbx[ce+2], c3 = cbx[ce+3];
      const double yy1 = fmax(by1, c0), xx1 = fmax(bx1, c1);
      const double yy2 = fmin(by2, c2), xx2 = fmin(bx2, c3);
      const double inter = fmax(yy2-yy1, 0.0) * fmax(xx2-xx1, 0.0);
      const double a2 = fmax(c2-c0, 0.0) * fmax(c3-c1, 0.0);
      const double iou = inter / (a1 + a2 - inter + 1e-8);
      if (iou > 0.7) bits |= (1ull << bcol);
    }
  }
  rowbits[(size_t)r*128 + g*16 + w] = bits;
}

// ---------------- greedy scan with suppression bitmap ----------------
__global__ __launch_bounds__(64) void greedy(
    const unsigned long long* __restrict__ skeys, const double* __restrict__ sboxd,
    const unsigned long long* __restrict__ rowbits, float* __restrict__ outp)
{
  const int t = threadIdx.x;
  const unsigned long long KEYTH = dkey(-5.0e8);
  int bad = PRE_NMS;
  for (int j = t; j < PRE_NMS; j += 64){
    if (skeys[j] <= KEYTH){ bad = j; break; }
  }
  #pragma unroll
  for (int off = 32; off > 0; off >>= 1){
    const int o = __shfl_down(bad, off, 64);
    bad = (o < bad) ? o : bad;
  }
  const int ilim = __builtin_amdgcn_readfirstlane(bad);

  unsigned long long s0 = 0ull, s1 = 0ull;
  int emitted = 0;
  for (int i = 0; i < ilim && emitted < POST_NMS; ++i){
    const int w = i >> 6, b = i & 63;
    const unsigned long long w0 = shfl_u64(s0, w & 63);
    const unsigned long long w1 = shfl_u64(s1, (w - 64) & 63);
    const unsigned long long word = (w < 64) ? w0 : w1;
    if (!((word >> b) & 1ull)){
      if (t < 4) outp[4*emitted + t] = (float)sboxd[(size_t)i*4 + t];
      s0 |= rowbits[(size_t)i*128 + t];
      if (t < 30) s1 |= rowbits[(size_t)i*128 + 64 + t];
      ++emitted;
    }
  }
  for (int r = emitted; r < POST_NMS; ++r)
    if (t < 4) outp[4*r + t] = 0.f;
}

extern "C" void kernel_launch(void* const* d_in, const int* in_sizes, int n_in,
                              void* d_out, int out_size, void* d_ws, size_t ws_size,
                              hipStream_t stream)
{
  const float* fm   = (const float*)d_in[1];
  const float* amap = (const float*)d_in[2];
  const float* W1   = (const float*)d_in[4];
  const float* b1   = (const float*)d_in[5];
  const float* Wc   = (const float*)d_in[6];
  const float* bc   = (const float*)d_in[7];
  const float* Wr   = (const float*)d_in[8];
  const float* br   = (const float*)d_in[9];
  float* out = (float*)d_out;

  char* base = (char*)d_ws;
  size_t off = 0;
  auto A = [&](size_t n) -> char* {
    char* p = base + off;
    off = (off + n + 255) & ~(size_t)255;
    return p;
  };
  double* yd      = (double*)A(65536000);
  double* fmd     = (double*)A(65536000);
  double* WcT     = (double*)A(36864);
  double* WrT     = (double*)A(147456);
  double* scored  = (double*)A(1152000);
  double* regd    = (double*)A(4608000);
  unsigned* histc = (unsigned*)A(524328);        // hist1|hist2|cnt|meta contiguous
  double* boxesd              = (double*)A(4608000);
  unsigned long long* nmskey  = (unsigned long long*)A(1152000);
  unsigned* key32             = (unsigned*)A(576000);
  double* selboxd             = (double*)A(192000);
  unsigned long long* selkey  = (unsigned long long*)A(48000);
  unsigned long long* skeys   = (unsigned long long*)A(48000);
  double* sboxd               = (double*)A(192000);
  unsigned long long* rowbits = (unsigned long long*)A(6144000);
  int* eqidx                  = (int*)A(32768);

  unsigned* hist1 = histc;
  unsigned* hist2 = histc + 65536;
  int* cnt        = (int*)(histc + 131072);
  int* meta       = cnt + 2;

  hipMemsetAsync(histc, 0, (size_t)524328, stream);

  hipLaunchKernelGGL(prep_all, dim3(8090), dim3(256), 0, stream,
                     fm, Wc, Wr, fmd, WcT, WrT);
  hipLaunchKernelGGL(conv_gemm, dim3(1000), dim3(256), 0, stream, fmd, W1, b1, yd);
  hipLaunchKernelGGL(head2, dim3(1000), dim3(256), 0, stream, yd, WcT, bc, WrT, br, out, scored, regd);
  hipLaunchKernelGGL(decode_hist, dim3((NANCH + 255)/256), dim3(256), 0, stream,
                     amap, scored, regd, boxesd, key32, nmskey, hist1);
  hipLaunchKernelGGL(scan_hi, dim3(1), dim3(1024), 0, stream, hist1, meta);
  hipLaunchKernelGGL(hist_lo, dim3((NANCH + 255)/256), dim3(256), 0, stream, key32, meta, hist2);
  hipLaunchKernelGGL(scan_lo, dim3(1), dim3(1024), 0, stream, hist2, meta);
  hipLaunchKernelGGL(compact_k, dim3((NANCH + 255)/256), dim3(256), 0, stream,
                     key32, nmskey, boxesd, meta, cnt, selboxd, selkey, eqidx);
  hipLaunchKernelGGL(rankeq, dim3(1), dim3(256), 0, stream,
                     scored, boxesd, nmskey, meta, cnt, eqidx, selboxd, selkey);
  hipLaunchKernelGGL(rank_scatter, dim3((PRE_NMS + 255)/256), dim3(256), 0, stream,
                     selkey, selboxd, skeys, sboxd);
  hipLaunchKernelGGL(iou_bitmap, dim3(375, 6), dim3(256), 0, stream, sboxd, rowbits);
  hipLaunchKernelGGL(greedy, dim3(1), dim3(64), 0, stream, skeys, sboxd, rowbits, out + 720000);
}